// Round 13
// baseline (202.142 us; speedup 1.0000x reference)
//
#include <hip/hip_runtime.h>
#include <hip/hip_bf16.h>

#define NTOK 8192
#define DIN  1024
#define HID  2048
#define OUTD 1024
#define NEXP 8
#define BM 128
#define MAXT (NTOK / BM + NEXP)   // 72 M-tiles max

typedef short short8 __attribute__((ext_vector_type(8)));
typedef float f32x4 __attribute__((ext_vector_type(4)));

static __device__ __forceinline__ unsigned short f2bf(float f) {
  union { __hip_bfloat16 b; unsigned short u; } cv;
  cv.b = __float2bfloat16(f);
  return cv.u;
}

static __device__ __forceinline__ void gload_lds16(const void* g, void* l) {
  __builtin_amdgcn_global_load_lds(
      (const __attribute__((address_space(1))) void*)g,
      (__attribute__((address_space(3))) void*)l, 16, 0, 0);
}

// ---------------- prep: W [E][R][C] fp32 -> WT [E][C][R] bf16 ----------------
// 64x64 tiles; float4 (16B) reads, short8 (16B) writes.
__global__ __launch_bounds__(256) void transpose_convert_kernel(
    const float* __restrict__ W, unsigned short* __restrict__ WT, int R, int C) {
  __shared__ float tile[64][65];
  const int e = blockIdx.z;
  const int c0 = blockIdx.x * 64, r0 = blockIdx.y * 64;
  const int lr = threadIdx.x >> 4;    // 0..15
  const int fc = threadIdx.x & 15;    // float4 column
  const float* Wp = W + ((size_t)e * R + r0) * C + c0;
#pragma unroll
  for (int i = 0; i < 4; ++i) {
    int r = lr + i * 16;
    float4 v = *(const float4*)(Wp + (size_t)r * C + fc * 4);
    tile[r][fc * 4 + 0] = v.x; tile[r][fc * 4 + 1] = v.y;
    tile[r][fc * 4 + 2] = v.z; tile[r][fc * 4 + 3] = v.w;
  }
  __syncthreads();
  // write: thread -> (cc = output row = source col, rc = 8-row source chunk)
  unsigned short* Op = WT + ((size_t)e * C + c0) * R + r0;
  const int cc0 = threadIdx.x >> 3;   // 0..31
  const int rc = threadIdx.x & 7;     // 0..7 (8 source rows each)
#pragma unroll
  for (int i = 0; i < 2; ++i) {
    int cc = cc0 + i * 32;
    short8 o;
#pragma unroll
    for (int j = 0; j < 8; ++j) o[j] = (short)f2bf(tile[rc * 8 + j][cc]);
    *(short8*)(Op + (size_t)cc * R + rc * 8) = o;   // 16B/lane, coalesced
  }
}

// ---------------- fused: x fp32 -> bf16  +  router (fp32, NO atomics) ------
__global__ __launch_bounds__(256) void fused_router_kernel(
    const float* __restrict__ x, const float* __restrict__ Wr,
    const float* __restrict__ br, unsigned short* __restrict__ xb,
    float* __restrict__ probs_out, int* __restrict__ routes) {
  __shared__ float WrL[NEXP][DIN];   // transposed router weights, 32 KB
  const int tid = threadIdx.x;
#pragma unroll
  for (int rr = 0; rr < 4; ++rr) {
    int row = tid * 4 + rr;
    float4 w0 = *(const float4*)(Wr + (size_t)row * NEXP);
    float4 w1 = *(const float4*)(Wr + (size_t)row * NEXP + 4);
    WrL[0][row] = w0.x; WrL[1][row] = w0.y; WrL[2][row] = w0.z; WrL[3][row] = w0.w;
    WrL[4][row] = w1.x; WrL[5][row] = w1.y; WrL[6][row] = w1.z; WrL[7][row] = w1.w;
  }
  __syncthreads();

  const int lane = tid & 63;
  const int n = blockIdx.x * 4 + (tid >> 6);
  const float4* xr = (const float4*)(x + (size_t)n * DIN);
  ushort4* xo = (ushort4*)(xb + (size_t)n * DIN);
  float acc[NEXP];
#pragma unroll
  for (int e = 0; e < NEXP; ++e) acc[e] = 0.f;
#pragma unroll
  for (int j = 0; j < 4; ++j) {
    int idx = j * 64 + lane;            // coalesced: 64 consecutive float4
    float4 xv = xr[idx];
    ushort4 o = { f2bf(xv.x), f2bf(xv.y), f2bf(xv.z), f2bf(xv.w) };
    xo[idx] = o;
    int r0 = idx * 4;
#pragma unroll
    for (int e = 0; e < NEXP; ++e) {
      float4 wv = *(const float4*)&WrL[e][r0];
      acc[e] += xv.x * wv.x + xv.y * wv.y + xv.z * wv.z + xv.w * wv.w;
    }
  }
#pragma unroll
  for (int m = 1; m < 64; m <<= 1)
#pragma unroll
    for (int e = 0; e < NEXP; ++e) acc[e] += __shfl_xor(acc[e], m);

  if (lane == 0) {
    float lg[NEXP], p[NEXP];
    float mx = -1e30f;
#pragma unroll
    for (int e = 0; e < NEXP; ++e) { lg[e] = acc[e] + br[e]; mx = fmaxf(mx, lg[e]); }
    float s = 0.f;
#pragma unroll
    for (int e = 0; e < NEXP; ++e) { p[e] = expf(lg[e] - mx); s += p[e]; }
    float inv = 1.f / s;
    int best = 0; float bp = -1.f;
#pragma unroll
    for (int e = 0; e < NEXP; ++e) {
      p[e] *= inv;
      probs_out[(size_t)n * NEXP + e] = p[e];
      if (p[e] > bp) { bp = p[e]; best = e; }   // strict > : first-index tie-break
    }
    routes[n] = best;
  }
}

// ---------------- histogram + scan (single block, no atomics) ----------------
__global__ __launch_bounds__(256) void hist_scan_kernel(
    const int* __restrict__ routes, int* __restrict__ pad_off,
    int2* __restrict__ tile_table, float* __restrict__ counts_out) {
  __shared__ int wsum[4][NEXP];
  const int tid = threadIdx.x;
  const int lane = tid & 63, w = tid >> 6;
  int cnt[NEXP];
#pragma unroll
  for (int e = 0; e < NEXP; ++e) cnt[e] = 0;
#pragma unroll
  for (int j = 0; j < 8; ++j) {
    int4 r4 = ((const int4*)routes)[tid + 256 * j];
    int rr[4] = {r4.x, r4.y, r4.z, r4.w};
#pragma unroll
    for (int i = 0; i < 4; ++i)
#pragma unroll
      for (int e = 0; e < NEXP; ++e) cnt[e] += (rr[i] == e);  // no runtime idx -> regs
  }
#pragma unroll
  for (int m = 1; m < 64; m <<= 1)
#pragma unroll
    for (int e = 0; e < NEXP; ++e) cnt[e] += __shfl_xor(cnt[e], m);
  if (lane == 0)
#pragma unroll
    for (int e = 0; e < NEXP; ++e) wsum[w][e] = cnt[e];
  __syncthreads();
  if (tid == 0) {
    int off = 0, t = 0;
    for (int e = 0; e < NEXP; ++e) {
      int c = wsum[0][e] + wsum[1][e] + wsum[2][e] + wsum[3][e];
      pad_off[e] = off;
      counts_out[e] = (float)c;
      int tiles = (c + BM - 1) / BM;
      for (int i = 0; i < tiles; ++i) { tile_table[t] = make_int2(e, off + i * BM); ++t; }
      off += tiles * BM;
    }
    for (; t < MAXT; ++t) tile_table[t] = make_int2(-1, 0);
  }
}

// ---------------- build sorted token list (wave-aggregated atomics) ---------
__global__ void build_kernel(const int* __restrict__ routes,
                             const int* __restrict__ pad_off,
                             int* __restrict__ cursor,
                             int* __restrict__ sorted) {
  const int n = blockIdx.x * 256 + threadIdx.x;
  const int lane = threadIdx.x & 63;
  const int e = routes[n];
#pragma unroll
  for (int ex = 0; ex < NEXP; ++ex) {
    unsigned long long m = __ballot(e == ex);
    if (e == ex) {
      int leader = __ffsll(m) - 1;
      int rank = __popcll(m & ((1ull << lane) - 1ull));
      int b = 0;
      if (rank == 0) b = atomicAdd(&cursor[ex], (int)__popcll(m));
      b = __shfl(b, leader);
      sorted[pad_off[ex] + b + rank] = n;
    }
  }
}

// ===== grouped GEMM: 128x128 tile, BK=64, 4 waves, 4-phase, 2 blocks/CU =====
// Same template as R12 with the TAIL RACE FIXED: the steady-state vmcnt(4)
// at q4 is exact only while q3/q4 keep issuing stages. At t==NKT-2 those are
// skipped, so outstanding = [B0(L),A1(L),B1(L),A0(L)] (L=NKT-1) and vmcnt(4)
// left B1(L),A0(L) IN FLIGHT while iteration L read them (absmax 0.0156 ->
// 0.92 at 2 blocks/CU: contention stretched the window). Fix: vmcnt(0) when
// no q3/q4 stages were issued (t+2>=NKT) -- drains the pipe exactly when it
// stops refilling; steady state untouched.
// Phase p: [ds_read frags(p); stage; barrier; lgkmcnt(0); MFMA(p)].
// Stage rotation per K-tile t: q1->B1(t+1)@dn, q2->A0(t+1)@dn,
// q3->B0(t+2)@d, q4->A1(t+2)@d; vmcnt(4) at q4 completes through A0(t+1).
// Swizzle (G4): chunk ^= row&7 on pre-swizzled gload source AND
// byte ^= (fr&7)<<4 on ds_read (row bases x16 => row&7 == fr&7) (rule #21).
// MODE 0: A = xb gathered, out = relu(acc+b1) -> bf16 hbuf[token][NDIM]
// MODE 1: A = hbuf gathered, out = acc+b2     -> fp32 out[token][NDIM]
#define PHASE_SYNC() do { \
    __builtin_amdgcn_sched_barrier(0); \
    __builtin_amdgcn_s_barrier(); \
    __builtin_amdgcn_sched_barrier(0); \
    asm volatile("s_waitcnt lgkmcnt(0)" ::: "memory"); \
    __builtin_amdgcn_sched_barrier(0); } while (0)
#define VM4()  asm volatile("s_waitcnt vmcnt(4)" ::: "memory")
#define VM0()  asm volatile("s_waitcnt vmcnt(0)" ::: "memory")

#define LDA(MH, D) \
  _Pragma("unroll") for (int i_ = 0; i_ < 2; ++i_) \
  _Pragma("unroll") for (int k_ = 0; k_ < 2; ++k_) \
    fa[MH][i_][k_] = *(const short8*)&lds[(D) + (MH) * 4096 + aoff[i_][k_]];
#define LDB(NH, D) \
  _Pragma("unroll") for (int j_ = 0; j_ < 2; ++j_) \
  _Pragma("unroll") for (int k_ = 0; k_ < 2; ++k_) \
    fb[j_][k_] = *(const short8*)&lds[(D) + 8192 + (NH) * 4096 + boff[j_][k_]];
#define MFMA_QUAD(MH, NH) do { __builtin_amdgcn_s_setprio(1); \
  _Pragma("unroll") for (int i_ = 0; i_ < 2; ++i_) \
  _Pragma("unroll") for (int j_ = 0; j_ < 2; ++j_) \
  _Pragma("unroll") for (int k_ = 0; k_ < 2; ++k_) \
    acc[(MH) * 2 + i_][(NH) * 2 + j_] = __builtin_amdgcn_mfma_f32_16x16x32_bf16( \
        fa[MH][i_][k_], fb[j_][k_], acc[(MH) * 2 + i_][(NH) * 2 + j_], 0, 0, 0); \
  __builtin_amdgcn_s_setprio(0); } while (0)

template <int KDIM, int MODE, int NB>
__global__ __launch_bounds__(256, 2) void gemm_moe(
    const unsigned short* __restrict__ A, const unsigned short* __restrict__ WT,
    const float* __restrict__ bias, const int* __restrict__ sorted,
    const int2* __restrict__ tile_table, void* __restrict__ Cout, int NDIM) {
  __shared__ short lds[32768];   // 64 KB -> 2 blocks/CU

  // T1 bijective XCD swizzle (nwg % 8 == 0)
  const int nwg = NB * MAXT;
  const int bid = blockIdx.x;
  const int swz = (bid & 7) * (nwg >> 3) + (bid >> 3);
  const int2 tt = tile_table[swz / NB];
  if (tt.x < 0) return;
  const int expert = tt.x, mbase = tt.y;
  const int n0 = (swz % NB) * 128;
  const int tid = threadIdx.x, lane = tid & 63, w = tid >> 6;
  const int qm = w >> 1, qn = w & 1;       // wave grid 2M x 2N within a quadrant
  const int fr = lane & 15, klo = lane >> 4;

  // ---- staging descriptors: 2 x 16B chunks per thread per half-tile ----
  const short* srcA[2][2];   // [half][load]
  const short* srcB[2][2];
  int dstoff[2];
#pragma unroll
  for (int l = 0; l < 2; ++l) {
    const int ch = l * 256 + tid;                       // chunk 0..511 (row-major)
    const int row = ch >> 3;                            // 64 rows x 8 chunks
    const int csw = ((ch & 7) ^ (row & 7)) * 8;         // inverse-swizzled source
    dstoff[l] = ch * 8;                                 // linear LDS dest (shorts)
#pragma unroll
    for (int h = 0; h < 2; ++h) {
      int tok = sorted[mbase + h * 64 + row];
      if (tok < 0) tok = 0;                             // pad: dropped at store
      srcA[h][l] = (const short*)A + (size_t)tok * KDIM + csw;
      srcB[h][l] = (const short*)WT + ((size_t)expert * NDIM + n0 + h * 64 + row) * KDIM + csw;
    }
  }
  auto stA = [&](int doff, int h, int kt) {
    const int base = doff + h * 4096, ko = kt * 64;
#pragma unroll
    for (int l = 0; l < 2; ++l) gload_lds16(srcA[h][l] + ko, &lds[base + dstoff[l]]);
  };
  auto stB = [&](int doff, int h, int kt) {
    const int base = doff + 8192 + h * 4096, ko = kt * 64;
#pragma unroll
    for (int l = 0; l < 2; ++l) gload_lds16(srcB[h][l] + ko, &lds[base + dstoff[l]]);
  };

  // ---- fragment ds_read offsets (shorts, within 8KB half, swizzled) ----
  const int rsw = (fr & 7) << 4;            // row&7 == fr&7 (bases are x16)
  int aoff[2][2], boff[2][2];
#pragma unroll
  for (int i = 0; i < 2; ++i)
#pragma unroll
    for (int k = 0; k < 2; ++k) {
      int b = (qm * 32 + i * 16 + fr) * 128 + k * 64 + klo * 16;
      aoff[i][k] = (b ^ rsw) >> 1;
    }
#pragma unroll
  for (int j = 0; j < 2; ++j)
#pragma unroll
    for (int k = 0; k < 2; ++k) {
      int b = (qn * 32 + j * 16 + fr) * 128 + k * 64 + klo * 16;
      boff[j][k] = (b ^ rsw) >> 1;
    }

  f32x4 acc[4][4];
#pragma unroll
  for (int mi = 0; mi < 4; ++mi)
#pragma unroll
    for (int nj = 0; nj < 4; ++nj) acc[mi][nj] = (f32x4){0.f, 0.f, 0.f, 0.f};
  short8 fa[2][2][2], fb[2][2];

  constexpr int NKT = KDIM / 64;
  // prologue: tile0 all halves + B0(1), A1(1)  (order matters for vmcnt)
  stB(0, 0, 0); stA(0, 1, 0); stB(0, 1, 0); stA(0, 0, 0);
  stB(16384, 0, 1); stA(16384, 1, 1);
  VM4();
  __builtin_amdgcn_s_barrier();
  __builtin_amdgcn_sched_barrier(0);

  for (int t = 0; t < NKT; ++t) {
    const int d = (t & 1) * 16384;
    const int dn = 16384 - d;
    // q1 (M0,N0): read A0,B0; stage B1(t+1)@dn
    LDA(0, d); LDB(0, d);
    if (t + 1 < NKT) stB(dn, 1, t + 1);
    PHASE_SYNC();
    MFMA_QUAD(0, 0);
    // q2 (M1,N0): read A1; stage A0(t+1)@dn
    LDA(1, d);
    if (t + 1 < NKT) stA(dn, 0, t + 1);
    PHASE_SYNC();
    MFMA_QUAD(1, 0);
    // q3 (M1,N1): read B1; stage B0(t+2)@d
    LDB(1, d);
    if (t + 2 < NKT) stB(d, 0, t + 2);
    PHASE_SYNC();
    MFMA_QUAD(1, 1);
    // q4 (M0,N1): stage A1(t+2)@d; exact wait (TAIL FIX: vmcnt(0) once the
    // q3/q4 refills stop, else vmcnt(4) completes exactly through A0(t+1))
    if (t + 2 < NKT) { stA(d, 1, t + 2); VM4(); } else { VM0(); }
    PHASE_SYNC();
    MFMA_QUAD(0, 1);
  }

  // ---- epilogue: scatter rows to token-indexed buffer ----
  const int fq = lane >> 4;
#pragma unroll
  for (int mi = 0; mi < 4; ++mi) {
    const int rbase = mbase + (mi >> 1) * 64 + qm * 32 + (mi & 1) * 16 + fq * 4;
    int tok[4];
#pragma unroll
    for (int r = 0; r < 4; ++r) tok[r] = sorted[rbase + r];
#pragma unroll
    for (int nj = 0; nj < 4; ++nj) {
      const int col = n0 + (nj >> 1) * 64 + qn * 32 + (nj & 1) * 16 + fr;
      const float bv = bias[(size_t)expert * NDIM + col];
#pragma unroll
      for (int r = 0; r < 4; ++r) {
        if (tok[r] < 0) continue;           // pad row
        float v = acc[mi][nj][r] + bv;
        if (MODE == 0) {
          ((unsigned short*)Cout)[(size_t)tok[r] * NDIM + col] = f2bf(fmaxf(v, 0.f));
        } else {
          ((float*)Cout)[(size_t)tok[r] * NDIM + col] = v;
        }
      }
    }
  }
}

extern "C" void kernel_launch(void* const* d_in, const int* in_sizes, int n_in,
                              void* d_out, int out_size, void* d_ws, size_t ws_size,
                              hipStream_t stream) {
  const float* x  = (const float*)d_in[0];
  const float* Wr = (const float*)d_in[1];
  const float* br = (const float*)d_in[2];
  const float* W1 = (const float*)d_in[3];
  const float* b1 = (const float*)d_in[4];
  const float* W2 = (const float*)d_in[5];
  const float* b2 = (const float*)d_in[6];

  float* out_y      = (float*)d_out;                      // [N,O]
  float* out_probs  = out_y + (size_t)NTOK * OUTD;        // [N,E]
  float* out_counts = out_probs + (size_t)NTOK * NEXP;    // [E]

  char* ws = (char*)d_ws;
  unsigned short* xb   = (unsigned short*)(ws);                                  // 16 MB
  unsigned short* w1t  = (unsigned short*)(ws + 16777216ULL);                    // 32 MB
  unsigned short* w2t  = (unsigned short*)(ws + 50331648ULL);                    // 32 MB
  unsigned short* hbuf = (unsigned short*)(ws + 83886080ULL);                    // 32 MB (token-indexed)
  char* p = ws + 117440512ULL;
  int* routes   = (int*)p; p += 32768;
  int* sorted   = (int*)p; p += (NTOK + NEXP * BM) * 4;
  int* cursor   = (int*)p; p += 256;
  int* pad_off  = (int*)p; p += 256;
  int2* tt      = (int2*)p;

  hipMemsetAsync(sorted, 0xFF, (NTOK + NEXP * BM) * sizeof(int), stream);
  hipMemsetAsync(cursor, 0, 256, stream);

  transpose_convert_kernel<<<dim3(HID / 64, DIN / 64, NEXP), 256, 0, stream>>>(W1, w1t, DIN, HID);
  transpose_convert_kernel<<<dim3(OUTD / 64, HID / 64, NEXP), 256, 0, stream>>>(W2, w2t, HID, OUTD);
  fused_router_kernel<<<NTOK / 4, 256, 0, stream>>>(x, Wr, br, xb, out_probs, routes);
  hist_scan_kernel<<<1, 256, 0, stream>>>(routes, pad_off, tt, out_counts);
  build_kernel<<<NTOK / 256, 256, 0, stream>>>(routes, pad_off, cursor, sorted);
  gemm_moe<DIN, 0, HID / 128><<<(HID / 128) * MAXT, 256, 0, stream>>>(
      xb, w1t, b1, sorted, tt, hbuf, HID);
  gemm_moe<HID, 1, OUTD / 128><<<(OUTD / 128) * MAXT, 256, 0, stream>>>(
      hbuf, w2t, b2, sorted, tt, out_y, OUTD);
}

// Round 14
// 189.700 us; speedup vs baseline: 1.0656x; 1.0656x over previous
//
#include <hip/hip_runtime.h>
#include <hip/hip_bf16.h>

#define NTOK 8192
#define DIN  1024
#define HID  2048
#define OUTD 1024
#define NEXP 8
#define BM 128
#define MAXT (NTOK / BM + NEXP)   // 72 M-tiles max

typedef short short8 __attribute__((ext_vector_type(8)));
typedef float f32x4 __attribute__((ext_vector_type(4)));

static __device__ __forceinline__ unsigned short f2bf(float f) {
  union { __hip_bfloat16 b; unsigned short u; } cv;
  cv.b = __float2bfloat16(f);
  return cv.u;
}

static __device__ __forceinline__ void gload_lds16(const void* g, void* l) {
  __builtin_amdgcn_global_load_lds(
      (const __attribute__((address_space(1))) void*)g,
      (__attribute__((address_space(3))) void*)l, 16, 0, 0);
}

// ================= fused prep: W1-transpose | W2-transpose | router =========
// One launch, block-range dispatch; the three parts are independent and run
// concurrently (removes 2 launch gaps + serial BW ramps). 32 KB LDS union.
// transpose: W [E][R][C] fp32 -> WT [E][C][R] bf16, 64x64 tiles, 16B r/w.
// router: x fp32 -> xb bf16 (coalesced) + fp32 softmax probs + argmax routes.
#define T1BLK 4096   // (HID/64)*(DIN/64)*NEXP = 32*16*8
#define T2BLK 4096   // (OUTD/64)*(HID/64)*NEXP = 16*32*8

static __device__ void transpose_body(const float* __restrict__ W,
                                      unsigned short* __restrict__ WT,
                                      int R, int C, int bx, int by, int e,
                                      float* smemf) {
  float (*tile)[65] = (float(*)[65])smemf;
  const int c0 = bx * 64, r0 = by * 64;
  const int lr = threadIdx.x >> 4;    // 0..15
  const int fc = threadIdx.x & 15;    // float4 column
  const float* Wp = W + ((size_t)e * R + r0) * C + c0;
#pragma unroll
  for (int i = 0; i < 4; ++i) {
    int r = lr + i * 16;
    float4 v = *(const float4*)(Wp + (size_t)r * C + fc * 4);
    tile[r][fc * 4 + 0] = v.x; tile[r][fc * 4 + 1] = v.y;
    tile[r][fc * 4 + 2] = v.z; tile[r][fc * 4 + 3] = v.w;
  }
  __syncthreads();
  unsigned short* Op = WT + ((size_t)e * C + c0) * R + r0;
  const int cc0 = threadIdx.x >> 3;   // 0..31
  const int rc = threadIdx.x & 7;     // 8-row source chunk
#pragma unroll
  for (int i = 0; i < 2; ++i) {
    int cc = cc0 + i * 32;
    short8 o;
#pragma unroll
    for (int j = 0; j < 8; ++j) o[j] = (short)f2bf(tile[rc * 8 + j][cc]);
    *(short8*)(Op + (size_t)cc * R + rc * 8) = o;   // 16B/lane, coalesced
  }
}

static __device__ void router_body(const float* __restrict__ x,
                                   const float* __restrict__ Wr,
                                   const float* __restrict__ br,
                                   unsigned short* __restrict__ xb,
                                   float* __restrict__ probs_out,
                                   int* __restrict__ routes,
                                   int blk, float* smemf) {
  float (*WrL)[DIN] = (float(*)[DIN])smemf;   // [NEXP][DIN] = 32 KB
  const int tid = threadIdx.x;
#pragma unroll
  for (int rr = 0; rr < 4; ++rr) {
    int row = tid * 4 + rr;
    float4 w0 = *(const float4*)(Wr + (size_t)row * NEXP);
    float4 w1 = *(const float4*)(Wr + (size_t)row * NEXP + 4);
    WrL[0][row] = w0.x; WrL[1][row] = w0.y; WrL[2][row] = w0.z; WrL[3][row] = w0.w;
    WrL[4][row] = w1.x; WrL[5][row] = w1.y; WrL[6][row] = w1.z; WrL[7][row] = w1.w;
  }
  __syncthreads();

  const int lane = tid & 63;
  const int n = blk * 4 + (tid >> 6);
  const float4* xr = (const float4*)(x + (size_t)n * DIN);
  ushort4* xo = (ushort4*)(xb + (size_t)n * DIN);
  float acc[NEXP];
#pragma unroll
  for (int e = 0; e < NEXP; ++e) acc[e] = 0.f;
#pragma unroll
  for (int j = 0; j < 4; ++j) {
    int idx = j * 64 + lane;            // coalesced: 64 consecutive float4
    float4 xv = xr[idx];
    ushort4 o = { f2bf(xv.x), f2bf(xv.y), f2bf(xv.z), f2bf(xv.w) };
    xo[idx] = o;
    int r0 = idx * 4;
#pragma unroll
    for (int e = 0; e < NEXP; ++e) {
      float4 wv = *(const float4*)&WrL[e][r0];
      acc[e] += xv.x * wv.x + xv.y * wv.y + xv.z * wv.z + xv.w * wv.w;
    }
  }
#pragma unroll
  for (int m = 1; m < 64; m <<= 1)
#pragma unroll
    for (int e = 0; e < NEXP; ++e) acc[e] += __shfl_xor(acc[e], m);

  if (lane == 0) {
    float lg[NEXP], p[NEXP];
    float mx = -1e30f;
#pragma unroll
    for (int e = 0; e < NEXP; ++e) { lg[e] = acc[e] + br[e]; mx = fmaxf(mx, lg[e]); }
    float s = 0.f;
#pragma unroll
    for (int e = 0; e < NEXP; ++e) { p[e] = expf(lg[e] - mx); s += p[e]; }
    float inv = 1.f / s;
    int best = 0; float bp = -1.f;
#pragma unroll
    for (int e = 0; e < NEXP; ++e) {
      p[e] *= inv;
      probs_out[(size_t)n * NEXP + e] = p[e];
      if (p[e] > bp) { bp = p[e]; best = e; }   // strict > : first-index tie-break
    }
    routes[n] = best;
  }
}

__global__ __launch_bounds__(256) void prep_kernel(
    const float* __restrict__ W1, unsigned short* __restrict__ w1t,
    const float* __restrict__ W2, unsigned short* __restrict__ w2t,
    const float* __restrict__ x, const float* __restrict__ Wr,
    const float* __restrict__ br, unsigned short* __restrict__ xb,
    float* __restrict__ probs_out, int* __restrict__ routes) {
  __shared__ float smemf[8192];   // 32 KB union
  const int bid = blockIdx.x;
  if (bid < T1BLK) {
    // W1: R=DIN(16 tiles), C=HID(32 tiles)
    int e = bid >> 9, rem = bid & 511;
    transpose_body(W1, w1t, DIN, HID, rem & 31, rem >> 5, e, smemf);
  } else if (bid < T1BLK + T2BLK) {
    // W2: R=HID(32 tiles), C=OUTD(16 tiles)
    int b = bid - T1BLK;
    int e = b >> 9, rem = b & 511;
    transpose_body(W2, w2t, HID, OUTD, rem & 15, rem >> 4, e, smemf);
  } else {
    router_body(x, Wr, br, xb, probs_out, routes, bid - T1BLK - T2BLK, smemf);
  }
}

// ---------------- histogram + scan + pad-fill (single block, no atomics) ----
// Also zeroes cursor and writes the pad slots of `sorted` (replaces the two
// hipMemsetAsync launches; everything re-done deterministically each call).
__global__ __launch_bounds__(256) void hist_scan_kernel(
    const int* __restrict__ routes, int* __restrict__ pad_off,
    int2* __restrict__ tile_table, float* __restrict__ counts_out,
    int* __restrict__ cursor, int* __restrict__ sorted) {
  __shared__ int wsum[4][NEXP];
  __shared__ int pstart[NEXP], pend[NEXP];
  const int tid = threadIdx.x;
  const int lane = tid & 63, w = tid >> 6;
  int cnt[NEXP];
#pragma unroll
  for (int e = 0; e < NEXP; ++e) cnt[e] = 0;
#pragma unroll
  for (int j = 0; j < 8; ++j) {
    int4 r4 = ((const int4*)routes)[tid + 256 * j];
    int rr[4] = {r4.x, r4.y, r4.z, r4.w};
#pragma unroll
    for (int i = 0; i < 4; ++i)
#pragma unroll
      for (int e = 0; e < NEXP; ++e) cnt[e] += (rr[i] == e);  // no runtime idx -> regs
  }
#pragma unroll
  for (int m = 1; m < 64; m <<= 1)
#pragma unroll
    for (int e = 0; e < NEXP; ++e) cnt[e] += __shfl_xor(cnt[e], m);
  if (lane == 0)
#pragma unroll
    for (int e = 0; e < NEXP; ++e) wsum[w][e] = cnt[e];
  __syncthreads();
  if (tid == 0) {
    int off = 0, t = 0;
    for (int e = 0; e < NEXP; ++e) {
      int c = wsum[0][e] + wsum[1][e] + wsum[2][e] + wsum[3][e];
      pad_off[e] = off;
      cursor[e] = 0;
      counts_out[e] = (float)c;
      int tiles = (c + BM - 1) / BM;
      pstart[e] = off + c;                 // pad range for this expert
      pend[e] = off + tiles * BM;
      for (int i = 0; i < tiles; ++i) { tile_table[t] = make_int2(e, off + i * BM); ++t; }
      off += tiles * BM;
    }
    for (; t < MAXT; ++t) tile_table[t] = make_int2(-1, 0);
  }
  __syncthreads();
#pragma unroll
  for (int e = 0; e < NEXP; ++e)
    for (int i = pstart[e] + tid; i < pend[e]; i += 256) sorted[i] = -1;
}

// ---------------- build sorted token list (wave-aggregated atomics) ---------
__global__ void build_kernel(const int* __restrict__ routes,
                             const int* __restrict__ pad_off,
                             int* __restrict__ cursor,
                             int* __restrict__ sorted) {
  const int n = blockIdx.x * 256 + threadIdx.x;
  const int lane = threadIdx.x & 63;
  const int e = routes[n];
#pragma unroll
  for (int ex = 0; ex < NEXP; ++ex) {
    unsigned long long m = __ballot(e == ex);
    if (e == ex) {
      int leader = __ffsll(m) - 1;
      int rank = __popcll(m & ((1ull << lane) - 1ull));
      int b = 0;
      if (rank == 0) b = atomicAdd(&cursor[ex], (int)__popcll(m));
      b = __shfl(b, leader);
      sorted[pad_off[ex] + b + rank] = n;
    }
  }
}

// ===== grouped GEMM: 128x128 tile, BK=64, 4 waves, 4-phase, 2 blocks/CU =====
// (byte-identical to R13 -- tail-race-fixed, refcheck'd absmax 0.0156)
// Phase p: [ds_read frags(p); stage; barrier; lgkmcnt(0); MFMA(p)].
// Stage rotation per K-tile t: q1->B1(t+1)@dn, q2->A0(t+1)@dn,
// q3->B0(t+2)@d, q4->A1(t+2)@d; vmcnt(4) at q4 completes through A0(t+1);
// tail: vmcnt(0) once q3/q4 refills stop (t+2>=NKT).
// Swizzle (G4): chunk ^= row&7 on pre-swizzled gload source AND
// byte ^= (fr&7)<<4 on ds_read (row bases x16 => row&7 == fr&7) (rule #21).
// MODE 0: A = xb gathered, out = relu(acc+b1) -> bf16 hbuf[token][NDIM]
// MODE 1: A = hbuf gathered, out = acc+b2     -> fp32 out[token][NDIM]
#define PHASE_SYNC() do { \
    __builtin_amdgcn_sched_barrier(0); \
    __builtin_amdgcn_s_barrier(); \
    __builtin_amdgcn_sched_barrier(0); \
    asm volatile("s_waitcnt lgkmcnt(0)" ::: "memory"); \
    __builtin_amdgcn_sched_barrier(0); } while (0)
#define VM4()  asm volatile("s_waitcnt vmcnt(4)" ::: "memory")
#define VM0()  asm volatile("s_waitcnt vmcnt(0)" ::: "memory")

#define LDA(MH, D) \
  _Pragma("unroll") for (int i_ = 0; i_ < 2; ++i_) \
  _Pragma("unroll") for (int k_ = 0; k_ < 2; ++k_) \
    fa[MH][i_][k_] = *(const short8*)&lds[(D) + (MH) * 4096 + aoff[i_][k_]];
#define LDB(NH, D) \
  _Pragma("unroll") for (int j_ = 0; j_ < 2; ++j_) \
  _Pragma("unroll") for (int k_ = 0; k_ < 2; ++k_) \
    fb[j_][k_] = *(const short8*)&lds[(D) + 8192 + (NH) * 4096 + boff[j_][k_]];
#define MFMA_QUAD(MH, NH) do { __builtin_amdgcn_s_setprio(1); \
  _Pragma("unroll") for (int i_ = 0; i_ < 2; ++i_) \
  _Pragma("unroll") for (int j_ = 0; j_ < 2; ++j_) \
  _Pragma("unroll") for (int k_ = 0; k_ < 2; ++k_) \
    acc[(MH) * 2 + i_][(NH) * 2 + j_] = __builtin_amdgcn_mfma_f32_16x16x32_bf16( \
        fa[MH][i_][k_], fb[j_][k_], acc[(MH) * 2 + i_][(NH) * 2 + j_], 0, 0, 0); \
  __builtin_amdgcn_s_setprio(0); } while (0)

template <int KDIM, int MODE, int NB>
__global__ __launch_bounds__(256, 2) void gemm_moe(
    const unsigned short* __restrict__ A, const unsigned short* __restrict__ WT,
    const float* __restrict__ bias, const int* __restrict__ sorted,
    const int2* __restrict__ tile_table, void* __restrict__ Cout, int NDIM) {
  __shared__ short lds[32768];   // 64 KB -> 2 blocks/CU

  // T1 bijective XCD swizzle (nwg % 8 == 0)
  const int nwg = NB * MAXT;
  const int bid = blockIdx.x;
  const int swz = (bid & 7) * (nwg >> 3) + (bid >> 3);
  const int2 tt = tile_table[swz / NB];
  if (tt.x < 0) return;
  const int expert = tt.x, mbase = tt.y;
  const int n0 = (swz % NB) * 128;
  const int tid = threadIdx.x, lane = tid & 63, w = tid >> 6;
  const int qm = w >> 1, qn = w & 1;       // wave grid 2M x 2N within a quadrant
  const int fr = lane & 15, klo = lane >> 4;

  // ---- staging descriptors: 2 x 16B chunks per thread per half-tile ----
  const short* srcA[2][2];   // [half][load]
  const short* srcB[2][2];
  int dstoff[2];
#pragma unroll
  for (int l = 0; l < 2; ++l) {
    const int ch = l * 256 + tid;                       // chunk 0..511 (row-major)
    const int row = ch >> 3;                            // 64 rows x 8 chunks
    const int csw = ((ch & 7) ^ (row & 7)) * 8;         // inverse-swizzled source
    dstoff[l] = ch * 8;                                 // linear LDS dest (shorts)
#pragma unroll
    for (int h = 0; h < 2; ++h) {
      int tok = sorted[mbase + h * 64 + row];
      if (tok < 0) tok = 0;                             // pad: dropped at store
      srcA[h][l] = (const short*)A + (size_t)tok * KDIM + csw;
      srcB[h][l] = (const short*)WT + ((size_t)expert * NDIM + n0 + h * 64 + row) * KDIM + csw;
    }
  }
  auto stA = [&](int doff, int h, int kt) {
    const int base = doff + h * 4096, ko = kt * 64;
#pragma unroll
    for (int l = 0; l < 2; ++l) gload_lds16(srcA[h][l] + ko, &lds[base + dstoff[l]]);
  };
  auto stB = [&](int doff, int h, int kt) {
    const int base = doff + 8192 + h * 4096, ko = kt * 64;
#pragma unroll
    for (int l = 0; l < 2; ++l) gload_lds16(srcB[h][l] + ko, &lds[base + dstoff[l]]);
  };

  // ---- fragment ds_read offsets (shorts, within 8KB half, swizzled) ----
  const int rsw = (fr & 7) << 4;            // row&7 == fr&7 (bases are x16)
  int aoff[2][2], boff[2][2];
#pragma unroll
  for (int i = 0; i < 2; ++i)
#pragma unroll
    for (int k = 0; k < 2; ++k) {
      int b = (qm * 32 + i * 16 + fr) * 128 + k * 64 + klo * 16;
      aoff[i][k] = (b ^ rsw) >> 1;
    }
#pragma unroll
  for (int j = 0; j < 2; ++j)
#pragma unroll
    for (int k = 0; k < 2; ++k) {
      int b = (qn * 32 + j * 16 + fr) * 128 + k * 64 + klo * 16;
      boff[j][k] = (b ^ rsw) >> 1;
    }

  f32x4 acc[4][4];
#pragma unroll
  for (int mi = 0; mi < 4; ++mi)
#pragma unroll
    for (int nj = 0; nj < 4; ++nj) acc[mi][nj] = (f32x4){0.f, 0.f, 0.f, 0.f};
  short8 fa[2][2][2], fb[2][2];

  constexpr int NKT = KDIM / 64;
  // prologue: tile0 all halves + B0(1), A1(1)  (order matters for vmcnt)
  stB(0, 0, 0); stA(0, 1, 0); stB(0, 1, 0); stA(0, 0, 0);
  stB(16384, 0, 1); stA(16384, 1, 1);
  VM4();
  __builtin_amdgcn_s_barrier();
  __builtin_amdgcn_sched_barrier(0);

  for (int t = 0; t < NKT; ++t) {
    const int d = (t & 1) * 16384;
    const int dn = 16384 - d;
    // q1 (M0,N0): read A0,B0; stage B1(t+1)@dn
    LDA(0, d); LDB(0, d);
    if (t + 1 < NKT) stB(dn, 1, t + 1);
    PHASE_SYNC();
    MFMA_QUAD(0, 0);
    // q2 (M1,N0): read A1; stage A0(t+1)@dn
    LDA(1, d);
    if (t + 1 < NKT) stA(dn, 0, t + 1);
    PHASE_SYNC();
    MFMA_QUAD(1, 0);
    // q3 (M1,N1): read B1; stage B0(t+2)@d
    LDB(1, d);
    if (t + 2 < NKT) stB(d, 0, t + 2);
    PHASE_SYNC();
    MFMA_QUAD(1, 1);
    // q4 (M0,N1): stage A1(t+2)@d; exact wait (tail: vmcnt(0) once refills stop)
    if (t + 2 < NKT) { stA(d, 1, t + 2); VM4(); } else { VM0(); }
    PHASE_SYNC();
    MFMA_QUAD(0, 1);
  }

  // ---- epilogue: scatter rows to token-indexed buffer ----
  const int fq = lane >> 4;
#pragma unroll
  for (int mi = 0; mi < 4; ++mi) {
    const int rbase = mbase + (mi >> 1) * 64 + qm * 32 + (mi & 1) * 16 + fq * 4;
    int tok[4];
#pragma unroll
    for (int r = 0; r < 4; ++r) tok[r] = sorted[rbase + r];
#pragma unroll
    for (int nj = 0; nj < 4; ++nj) {
      const int col = n0 + (nj >> 1) * 64 + qn * 32 + (nj & 1) * 16 + fr;
      const float bv = bias[(size_t)expert * NDIM + col];
#pragma unroll
      for (int r = 0; r < 4; ++r) {
        if (tok[r] < 0) continue;           // pad row
        float v = acc[mi][nj][r] + bv;
        if (MODE == 0) {
          ((unsigned short*)Cout)[(size_t)tok[r] * NDIM + col] = f2bf(fmaxf(v, 0.f));
        } else {
          ((float*)Cout)[(size_t)tok[r] * NDIM + col] = v;
        }
      }
    }
  }
}

extern "C" void kernel_launch(void* const* d_in, const int* in_sizes, int n_in,
                              void* d_out, int out_size, void* d_ws, size_t ws_size,
                              hipStream_t stream) {
  const float* x  = (const float*)d_in[0];
  const float* Wr = (const float*)d_in[1];
  const float* br = (const float*)d_in[2];
  const float* W1 = (const float*)d_in[3];
  const float* b1 = (const float*)d_in[4];
  const float* W2 = (const float*)d_in[5];
  const float* b2 = (const float*)d_in[6];

  float* out_y      = (float*)d_out;                      // [N,O]
  float* out_probs  = out_y + (size_t)NTOK * OUTD;        // [N,E]
  float* out_counts = out_probs + (size_t)NTOK * NEXP;    // [E]

  char* ws = (char*)d_ws;
  unsigned short* xb   = (unsigned short*)(ws);                                  // 16 MB
  unsigned short* w1t  = (unsigned short*)(ws + 16777216ULL);                    // 32 MB
  unsigned short* w2t  = (unsigned short*)(ws + 50331648ULL);                    // 32 MB
  unsigned short* hbuf = (unsigned short*)(ws + 83886080ULL);                    // 32 MB (token-indexed)
  char* p = ws + 117440512ULL;
  int* routes   = (int*)p; p += 32768;
  int* sorted   = (int*)p; p += (NTOK + NEXP * BM) * 4;
  int* cursor   = (int*)p; p += 256;
  int* pad_off  = (int*)p; p += 256;
  int2* tt      = (int2*)p;

  prep_kernel<<<T1BLK + T2BLK + NTOK / 4, 256, 0, stream>>>(
      W1, w1t, W2, w2t, x, Wr, br, xb, out_probs, routes);
  hist_scan_kernel<<<1, 256, 0, stream>>>(routes, pad_off, tt, out_counts,
                                          cursor, sorted);
  build_kernel<<<NTOK / 256, 256, 0, stream>>>(routes, pad_off, cursor, sorted);
  gemm_moe<DIN, 0, HID / 128><<<(HID / 128) * MAXT, 256, 0, stream>>>(
      xb, w1t, b1, sorted, tt, hbuf, HID);
  gemm_moe<HID, 1, OUTD / 128><<<(OUTD / 128) * MAXT, 256, 0, stream>>>(
      hbuf, w2t, b2, sorted, tt, out_y, OUTD);
}

// Round 15
// 183.415 us; speedup vs baseline: 1.1021x; 1.0343x over previous
//
#include <hip/hip_runtime.h>
#include <hip/hip_bf16.h>

#define NTOK 8192
#define DIN  1024
#define HID  2048
#define OUTD 1024
#define NEXP 8
#define BM 128
#define MAXT (NTOK / BM + NEXP)   // 72 M-tiles max

#define T1BLK 4096                // W1 transpose blocks: 32*16*8
#define RTBLK (NTOK / 4)          // router blocks: 2048
#define T2BLK 4096                // W2 transpose blocks: 16*32*8
#define G1BLK ((HID / 128) * MAXT)   // 1152 GEMM1 blocks (div by 8)

typedef short short8 __attribute__((ext_vector_type(8)));
typedef float f32x4 __attribute__((ext_vector_type(4)));

static __device__ __forceinline__ unsigned short f2bf(float f) {
  union { __hip_bfloat16 b; unsigned short u; } cv;
  cv.b = __float2bfloat16(f);
  return cv.u;
}

static __device__ __forceinline__ void gload_lds16(const void* g, void* l) {
  __builtin_amdgcn_global_load_lds(
      (const __attribute__((address_space(1))) void*)g,
      (__attribute__((address_space(3))) void*)l, 16, 0, 0);
}

// ---------------- transpose body: W [E][R][C] fp32 -> WT [E][C][R] bf16 -----
// 64x64 tiles; float4 (16B) reads, short8 (16B) writes.
static __device__ void transpose_body(const float* __restrict__ W,
                                      unsigned short* __restrict__ WT,
                                      int R, int C, int bx, int by, int e,
                                      float* smemf) {
  float (*tile)[65] = (float(*)[65])smemf;
  const int c0 = bx * 64, r0 = by * 64;
  const int lr = threadIdx.x >> 4;    // 0..15
  const int fc = threadIdx.x & 15;    // float4 column
  const float* Wp = W + ((size_t)e * R + r0) * C + c0;
#pragma unroll
  for (int i = 0; i < 4; ++i) {
    int r = lr + i * 16;
    float4 v = *(const float4*)(Wp + (size_t)r * C + fc * 4);
    tile[r][fc * 4 + 0] = v.x; tile[r][fc * 4 + 1] = v.y;
    tile[r][fc * 4 + 2] = v.z; tile[r][fc * 4 + 3] = v.w;
  }
  __syncthreads();
  unsigned short* Op = WT + ((size_t)e * C + c0) * R + r0;
  const int cc0 = threadIdx.x >> 3;   // 0..31
  const int rc = threadIdx.x & 7;     // 8-row source chunk
#pragma unroll
  for (int i = 0; i < 2; ++i) {
    int cc = cc0 + i * 32;
    short8 o;
#pragma unroll
    for (int j = 0; j < 8; ++j) o[j] = (short)f2bf(tile[rc * 8 + j][cc]);
    *(short8*)(Op + (size_t)cc * R + rc * 8) = o;   // 16B/lane, coalesced
  }
}

// ---------------- router body: x fp32 -> xb bf16 + probs + routes -----------
// WrL staged via register transpose + float4 writes (conflict-free; the old
// 32 scalar stride-4 writes were 8-way conflicted = the 2.1M counter).
static __device__ void router_body(const float* __restrict__ x,
                                   const float* __restrict__ Wr,
                                   const float* __restrict__ br,
                                   unsigned short* __restrict__ xb,
                                   float* __restrict__ probs_out,
                                   int* __restrict__ routes,
                                   int blk, float* smemf) {
  float (*WrL)[DIN] = (float(*)[DIN])smemf;   // [NEXP][DIN] = 32 KB
  const int tid = threadIdx.x;
  {
    const int r0 = tid * 4;
    float wlo[4][4], whi[4][4];
#pragma unroll
    for (int rr = 0; rr < 4; ++rr) {
      float4 v0 = *(const float4*)(Wr + (size_t)(r0 + rr) * NEXP);
      float4 v1 = *(const float4*)(Wr + (size_t)(r0 + rr) * NEXP + 4);
      wlo[rr][0] = v0.x; wlo[rr][1] = v0.y; wlo[rr][2] = v0.z; wlo[rr][3] = v0.w;
      whi[rr][0] = v1.x; whi[rr][1] = v1.y; whi[rr][2] = v1.z; whi[rr][3] = v1.w;
    }
#pragma unroll
    for (int e = 0; e < 4; ++e) {
      float4 o = { wlo[0][e], wlo[1][e], wlo[2][e], wlo[3][e] };
      *(float4*)&WrL[e][r0] = o;                 // lane stride 16B: no conflict
      float4 o2 = { whi[0][e], whi[1][e], whi[2][e], whi[3][e] };
      *(float4*)&WrL[e + 4][r0] = o2;
    }
  }
  __syncthreads();

  const int lane = tid & 63;
  const int n = blk * 4 + (tid >> 6);
  const float4* xr = (const float4*)(x + (size_t)n * DIN);
  ushort4* xo = (ushort4*)(xb + (size_t)n * DIN);
  float acc[NEXP];
#pragma unroll
  for (int e = 0; e < NEXP; ++e) acc[e] = 0.f;
#pragma unroll
  for (int j = 0; j < 4; ++j) {
    int idx = j * 64 + lane;            // coalesced: 64 consecutive float4
    float4 xv = xr[idx];
    ushort4 o = { f2bf(xv.x), f2bf(xv.y), f2bf(xv.z), f2bf(xv.w) };
    xo[idx] = o;
    int r0 = idx * 4;
#pragma unroll
    for (int e = 0; e < NEXP; ++e) {
      float4 wv = *(const float4*)&WrL[e][r0];
      acc[e] += xv.x * wv.x + xv.y * wv.y + xv.z * wv.z + xv.w * wv.w;
    }
  }
#pragma unroll
  for (int m = 1; m < 64; m <<= 1)
#pragma unroll
    for (int e = 0; e < NEXP; ++e) acc[e] += __shfl_xor(acc[e], m);

  if (lane == 0) {
    float lg[NEXP], p[NEXP];
    float mx = -1e30f;
#pragma unroll
    for (int e = 0; e < NEXP; ++e) { lg[e] = acc[e] + br[e]; mx = fmaxf(mx, lg[e]); }
    float s = 0.f;
#pragma unroll
    for (int e = 0; e < NEXP; ++e) { p[e] = expf(lg[e] - mx); s += p[e]; }
    float inv = 1.f / s;
    int best = 0; float bp = -1.f;
#pragma unroll
    for (int e = 0; e < NEXP; ++e) {
      p[e] *= inv;
      probs_out[(size_t)n * NEXP + e] = p[e];
      if (p[e] > bp) { bp = p[e]; best = e; }   // strict > : first-index tie-break
    }
    routes[n] = best;
  }
}

// ============ prep1: W1-transpose | router (critical path for GEMM1) =======
__global__ __launch_bounds__(256) void prep1_kernel(
    const float* __restrict__ W1, unsigned short* __restrict__ w1t,
    const float* __restrict__ x, const float* __restrict__ Wr,
    const float* __restrict__ br, unsigned short* __restrict__ xb,
    float* __restrict__ probs_out, int* __restrict__ routes) {
  __shared__ float smemf[8192];   // 32 KB union
  const int bid = blockIdx.x;
  if (bid < T1BLK) {
    int e = bid >> 9, rem = bid & 511;   // W1: R=DIN(16 tiles), C=HID(32 tiles)
    transpose_body(W1, w1t, DIN, HID, rem & 31, rem >> 5, e, smemf);
  } else {
    router_body(x, Wr, br, xb, probs_out, routes, bid - T1BLK, smemf);
  }
}

// ---------------- histogram + scan + pad-fill (single block, no atomics) ----
__global__ __launch_bounds__(256) void hist_scan_kernel(
    const int* __restrict__ routes, int* __restrict__ pad_off,
    int2* __restrict__ tile_table, float* __restrict__ counts_out,
    int* __restrict__ cursor, int* __restrict__ sorted) {
  __shared__ int wsum[4][NEXP];
  __shared__ int pstart[NEXP], pend[NEXP];
  const int tid = threadIdx.x;
  const int lane = tid & 63, w = tid >> 6;
  int cnt[NEXP];
#pragma unroll
  for (int e = 0; e < NEXP; ++e) cnt[e] = 0;
#pragma unroll
  for (int j = 0; j < 8; ++j) {
    int4 r4 = ((const int4*)routes)[tid + 256 * j];
    int rr[4] = {r4.x, r4.y, r4.z, r4.w};
#pragma unroll
    for (int i = 0; i < 4; ++i)
#pragma unroll
      for (int e = 0; e < NEXP; ++e) cnt[e] += (rr[i] == e);  // no runtime idx -> regs
  }
#pragma unroll
  for (int m = 1; m < 64; m <<= 1)
#pragma unroll
    for (int e = 0; e < NEXP; ++e) cnt[e] += __shfl_xor(cnt[e], m);
  if (lane == 0)
#pragma unroll
    for (int e = 0; e < NEXP; ++e) wsum[w][e] = cnt[e];
  __syncthreads();
  if (tid == 0) {
    int off = 0, t = 0;
    for (int e = 0; e < NEXP; ++e) {
      int c = wsum[0][e] + wsum[1][e] + wsum[2][e] + wsum[3][e];
      pad_off[e] = off;
      cursor[e] = 0;
      counts_out[e] = (float)c;
      int tiles = (c + BM - 1) / BM;
      pstart[e] = off + c;                 // pad range for this expert
      pend[e] = off + tiles * BM;
      for (int i = 0; i < tiles; ++i) { tile_table[t] = make_int2(e, off + i * BM); ++t; }
      off += tiles * BM;
    }
    for (; t < MAXT; ++t) tile_table[t] = make_int2(-1, 0);
  }
  __syncthreads();
#pragma unroll
  for (int e = 0; e < NEXP; ++e)
    for (int i = pstart[e] + tid; i < pend[e]; i += 256) sorted[i] = -1;
}

// ---------------- build sorted token list (wave-aggregated atomics) ---------
__global__ void build_kernel(const int* __restrict__ routes,
                             const int* __restrict__ pad_off,
                             int* __restrict__ cursor,
                             int* __restrict__ sorted) {
  const int n = blockIdx.x * 256 + threadIdx.x;
  const int lane = threadIdx.x & 63;
  const int e = routes[n];
#pragma unroll
  for (int ex = 0; ex < NEXP; ++ex) {
    unsigned long long m = __ballot(e == ex);
    if (e == ex) {
      int leader = __ffsll(m) - 1;
      int rank = __popcll(m & ((1ull << lane) - 1ull));
      int b = 0;
      if (rank == 0) b = atomicAdd(&cursor[ex], (int)__popcll(m));
      b = __shfl(b, leader);
      sorted[pad_off[ex] + b + rank] = n;
    }
  }
}

// ===== grouped GEMM body: 128x128 tile, BK=64, 4 waves, 4-phase =============
// (byte-identical schedule to R13/R14 -- tail-race-fixed, refcheck'd)
// Phase p: [ds_read frags(p); stage; barrier; lgkmcnt(0); MFMA(p)].
// Stage rotation per K-tile t: q1->B1(t+1)@dn, q2->A0(t+1)@dn,
// q3->B0(t+2)@d, q4->A1(t+2)@d; vmcnt(4) at q4 completes through A0(t+1);
// tail: vmcnt(0) once q3/q4 refills stop (t+2>=NKT).
// Swizzle (G4): chunk ^= row&7 on pre-swizzled gload source AND
// byte ^= (fr&7)<<4 on ds_read (row bases x16 => row&7 == fr&7) (rule #21).
#define PHASE_SYNC() do { \
    __builtin_amdgcn_sched_barrier(0); \
    __builtin_amdgcn_s_barrier(); \
    __builtin_amdgcn_sched_barrier(0); \
    asm volatile("s_waitcnt lgkmcnt(0)" ::: "memory"); \
    __builtin_amdgcn_sched_barrier(0); } while (0)
#define VM4()  asm volatile("s_waitcnt vmcnt(4)" ::: "memory")
#define VM0()  asm volatile("s_waitcnt vmcnt(0)" ::: "memory")

#define LDA(MH, D) \
  _Pragma("unroll") for (int i_ = 0; i_ < 2; ++i_) \
  _Pragma("unroll") for (int k_ = 0; k_ < 2; ++k_) \
    fa[MH][i_][k_] = *(const short8*)&lds[(D) + (MH) * 4096 + aoff[i_][k_]];
#define LDB(NH, D) \
  _Pragma("unroll") for (int j_ = 0; j_ < 2; ++j_) \
  _Pragma("unroll") for (int k_ = 0; k_ < 2; ++k_) \
    fb[j_][k_] = *(const short8*)&lds[(D) + 8192 + (NH) * 4096 + boff[j_][k_]];
#define MFMA_QUAD(MH, NH) do { __builtin_amdgcn_s_setprio(1); \
  _Pragma("unroll") for (int i_ = 0; i_ < 2; ++i_) \
  _Pragma("unroll") for (int j_ = 0; j_ < 2; ++j_) \
  _Pragma("unroll") for (int k_ = 0; k_ < 2; ++k_) \
    acc[(MH) * 2 + i_][(NH) * 2 + j_] = __builtin_amdgcn_mfma_f32_16x16x32_bf16( \
        fa[MH][i_][k_], fb[j_][k_], acc[(MH) * 2 + i_][(NH) * 2 + j_], 0, 0, 0); \
  __builtin_amdgcn_s_setprio(0); } while (0)

template <int KDIM, int MODE, int NB>
static __device__ void gemm_body(
    short* lds, int bid,
    const unsigned short* __restrict__ A, const unsigned short* __restrict__ WT,
    const float* __restrict__ bias, const int* __restrict__ sorted,
    const int2* __restrict__ tile_table, void* __restrict__ Cout, int NDIM) {
  // T1 bijective XCD swizzle (nwg % 8 == 0)
  const int nwg = NB * MAXT;
  const int swz = (bid & 7) * (nwg >> 3) + (bid >> 3);
  const int2 tt = tile_table[swz / NB];
  if (tt.x < 0) return;
  const int expert = tt.x, mbase = tt.y;
  const int n0 = (swz % NB) * 128;
  const int tid = threadIdx.x, lane = tid & 63, w = tid >> 6;
  const int qm = w >> 1, qn = w & 1;       // wave grid 2M x 2N within a quadrant
  const int fr = lane & 15, klo = lane >> 4;

  // ---- staging descriptors: 2 x 16B chunks per thread per half-tile ----
  const short* srcA[2][2];   // [half][load]
  const short* srcB[2][2];
  int dstoff[2];
#pragma unroll
  for (int l = 0; l < 2; ++l) {
    const int ch = l * 256 + tid;                       // chunk 0..511 (row-major)
    const int row = ch >> 3;                            // 64 rows x 8 chunks
    const int csw = ((ch & 7) ^ (row & 7)) * 8;         // inverse-swizzled source
    dstoff[l] = ch * 8;                                 // linear LDS dest (shorts)
#pragma unroll
    for (int h = 0; h < 2; ++h) {
      int tok = sorted[mbase + h * 64 + row];
      if (tok < 0) tok = 0;                             // pad: dropped at store
      srcA[h][l] = (const short*)A + (size_t)tok * KDIM + csw;
      srcB[h][l] = (const short*)WT + ((size_t)expert * NDIM + n0 + h * 64 + row) * KDIM + csw;
    }
  }
  auto stA = [&](int doff, int h, int kt) {
    const int base = doff + h * 4096, ko = kt * 64;
#pragma unroll
    for (int l = 0; l < 2; ++l) gload_lds16(srcA[h][l] + ko, &lds[base + dstoff[l]]);
  };
  auto stB = [&](int doff, int h, int kt) {
    const int base = doff + 8192 + h * 4096, ko = kt * 64;
#pragma unroll
    for (int l = 0; l < 2; ++l) gload_lds16(srcB[h][l] + ko, &lds[base + dstoff[l]]);
  };

  // ---- fragment ds_read offsets (shorts, within 8KB half, swizzled) ----
  const int rsw = (fr & 7) << 4;            // row&7 == fr&7 (bases are x16)
  int aoff[2][2], boff[2][2];
#pragma unroll
  for (int i = 0; i < 2; ++i)
#pragma unroll
    for (int k = 0; k < 2; ++k) {
      int b = (qm * 32 + i * 16 + fr) * 128 + k * 64 + klo * 16;
      aoff[i][k] = (b ^ rsw) >> 1;
    }
#pragma unroll
  for (int j = 0; j < 2; ++j)
#pragma unroll
    for (int k = 0; k < 2; ++k) {
      int b = (qn * 32 + j * 16 + fr) * 128 + k * 64 + klo * 16;
      boff[j][k] = (b ^ rsw) >> 1;
    }

  f32x4 acc[4][4];
#pragma unroll
  for (int mi = 0; mi < 4; ++mi)
#pragma unroll
    for (int nj = 0; nj < 4; ++nj) acc[mi][nj] = (f32x4){0.f, 0.f, 0.f, 0.f};
  short8 fa[2][2][2], fb[2][2];

  constexpr int NKT = KDIM / 64;
  // prologue: tile0 all halves + B0(1), A1(1)  (order matters for vmcnt)
  stB(0, 0, 0); stA(0, 1, 0); stB(0, 1, 0); stA(0, 0, 0);
  stB(16384, 0, 1); stA(16384, 1, 1);
  VM4();
  __builtin_amdgcn_s_barrier();
  __builtin_amdgcn_sched_barrier(0);

  for (int t = 0; t < NKT; ++t) {
    const int d = (t & 1) * 16384;
    const int dn = 16384 - d;
    // q1 (M0,N0): read A0,B0; stage B1(t+1)@dn
    LDA(0, d); LDB(0, d);
    if (t + 1 < NKT) stB(dn, 1, t + 1);
    PHASE_SYNC();
    MFMA_QUAD(0, 0);
    // q2 (M1,N0): read A1; stage A0(t+1)@dn
    LDA(1, d);
    if (t + 1 < NKT) stA(dn, 0, t + 1);
    PHASE_SYNC();
    MFMA_QUAD(1, 0);
    // q3 (M1,N1): read B1; stage B0(t+2)@d
    LDB(1, d);
    if (t + 2 < NKT) stB(d, 0, t + 2);
    PHASE_SYNC();
    MFMA_QUAD(1, 1);
    // q4 (M0,N1): stage A1(t+2)@d; exact wait (tail: vmcnt(0) once refills stop)
    if (t + 2 < NKT) { stA(d, 1, t + 2); VM4(); } else { VM0(); }
    PHASE_SYNC();
    MFMA_QUAD(0, 1);
  }

  // ---- epilogue: scatter rows to token-indexed buffer ----
  const int fq = lane >> 4;
#pragma unroll
  for (int mi = 0; mi < 4; ++mi) {
    const int rbase = mbase + (mi >> 1) * 64 + qm * 32 + (mi & 1) * 16 + fq * 4;
    int tok[4];
#pragma unroll
    for (int r = 0; r < 4; ++r) tok[r] = sorted[rbase + r];
#pragma unroll
    for (int nj = 0; nj < 4; ++nj) {
      const int col = n0 + (nj >> 1) * 64 + qn * 32 + (nj & 1) * 16 + fr;
      const float bv = bias[(size_t)expert * NDIM + col];
#pragma unroll
      for (int r = 0; r < 4; ++r) {
        if (tok[r] < 0) continue;           // pad row
        float v = acc[mi][nj][r] + bv;
        if (MODE == 0) {
          ((unsigned short*)Cout)[(size_t)tok[r] * NDIM + col] = f2bf(fmaxf(v, 0.f));
        } else {
          ((float*)Cout)[(size_t)tok[r] * NDIM + col] = v;
        }
      }
    }
  }
}

// ===== kernel B: GEMM1 blocks first, then W2-transpose blocks ===============
// GEMM1 (2 blocks/CU, 64KB LDS) leaves 32KB LDS free per CU: a transpose
// block co-resides as a 3rd block and soaks GEMM1's idle issue slots.
// w2t is complete at kernel end; GEMM2 (next launch) may read it (G16-safe).
__global__ __launch_bounds__(256, 2) void gemm1_t2_kernel(
    const unsigned short* __restrict__ xb, const unsigned short* __restrict__ w1t,
    const float* __restrict__ b1, const int* __restrict__ sorted,
    const int2* __restrict__ tile_table, unsigned short* __restrict__ hbuf,
    const float* __restrict__ W2, unsigned short* __restrict__ w2t) {
  __shared__ short lds[32768];   // 64 KB
  const int bid = blockIdx.x;
  if (bid < G1BLK) {
    gemm_body<DIN, 0, HID / 128>(lds, bid, xb, w1t, b1, sorted, tile_table,
                                 (void*)hbuf, HID);
  } else {
    int b = bid - G1BLK;          // W2: R=HID(32 tiles), C=OUTD(16 tiles)
    int e = b >> 9, rem = b & 511;
    transpose_body(W2, w2t, HID, OUTD, rem & 15, rem >> 4, e, (float*)lds);
  }
}

template <int KDIM, int MODE, int NB>
__global__ __launch_bounds__(256, 2) void gemm_moe(
    const unsigned short* __restrict__ A, const unsigned short* __restrict__ WT,
    const float* __restrict__ bias, const int* __restrict__ sorted,
    const int2* __restrict__ tile_table, void* __restrict__ Cout, int NDIM) {
  __shared__ short lds[32768];   // 64 KB -> 2 blocks/CU
  gemm_body<KDIM, MODE, NB>(lds, blockIdx.x, A, WT, bias, sorted, tile_table,
                            Cout, NDIM);
}

extern "C" void kernel_launch(void* const* d_in, const int* in_sizes, int n_in,
                              void* d_out, int out_size, void* d_ws, size_t ws_size,
                              hipStream_t stream) {
  const float* x  = (const float*)d_in[0];
  const float* Wr = (const float*)d_in[1];
  const float* br = (const float*)d_in[2];
  const float* W1 = (const float*)d_in[3];
  const float* b1 = (const float*)d_in[4];
  const float* W2 = (const float*)d_in[5];
  const float* b2 = (const float*)d_in[6];

  float* out_y      = (float*)d_out;                      // [N,O]
  float* out_probs  = out_y + (size_t)NTOK * OUTD;        // [N,E]
  float* out_counts = out_probs + (size_t)NTOK * NEXP;    // [E]

  char* ws = (char*)d_ws;
  unsigned short* xb   = (unsigned short*)(ws);                                  // 16 MB
  unsigned short* w1t  = (unsigned short*)(ws + 16777216ULL);                    // 32 MB
  unsigned short* w2t  = (unsigned short*)(ws + 50331648ULL);                    // 32 MB
  unsigned short* hbuf = (unsigned short*)(ws + 83886080ULL);                    // 32 MB (token-indexed)
  char* p = ws + 117440512ULL;
  int* routes   = (int*)p; p += 32768;
  int* sorted   = (int*)p; p += (NTOK + NEXP * BM) * 4;
  int* cursor   = (int*)p; p += 256;
  int* pad_off  = (int*)p; p += 256;
  int2* tt      = (int2*)p;

  prep1_kernel<<<T1BLK + RTBLK, 256, 0, stream>>>(
      W1, w1t, x, Wr, br, xb, out_probs, routes);
  hist_scan_kernel<<<1, 256, 0, stream>>>(routes, pad_off, tt, out_counts,
                                          cursor, sorted);
  build_kernel<<<NTOK / 256, 256, 0, stream>>>(routes, pad_off, cursor, sorted);
  gemm1_t2_kernel<<<G1BLK + T2BLK, 256, 0, stream>>>(
      xb, w1t, b1, sorted, tt, hbuf, W2, w2t);
  gemm_moe<HID, 1, OUTD / 128><<<(OUTD / 128) * MAXT, 256, 0, stream>>>(
      hbuf, w2t, b2, sorted, tt, out_y, OUTD);
}

// Round 16
// 171.144 us; speedup vs baseline: 1.1811x; 1.0717x over previous
//
#include <hip/hip_runtime.h>
#include <hip/hip_bf16.h>

#define NTOK 8192
#define DIN  1024
#define HID  2048
#define OUTD 1024
#define NEXP 8
#define BM 128
#define MAXT (NTOK / BM + NEXP)   // 72 M-tiles max

#define T1BLK 4096                // W1 transpose blocks: 32*16*8
#define RTBLK (NTOK / 4)          // router blocks: 2048
#define T2BLK 4096                // W2 transpose blocks: 16*32*8
#define G1BLK ((HID / 128) * MAXT)   // 1152 GEMM1 blocks (div by 8)

typedef short short8 __attribute__((ext_vector_type(8)));
typedef float f32x4 __attribute__((ext_vector_type(4)));

static __device__ __forceinline__ unsigned short f2bf(float f) {
  union { __hip_bfloat16 b; unsigned short u; } cv;
  cv.b = __float2bfloat16(f);
  return cv.u;
}

static __device__ __forceinline__ void gload_lds16(const void* g, void* l) {
  __builtin_amdgcn_global_load_lds(
      (const __attribute__((address_space(1))) void*)g,
      (__attribute__((address_space(3))) void*)l, 16, 0, 0);
}

// ---------------- transpose body: W [E][R][C] fp32 -> WT [E][C][R] bf16 -----
static __device__ void transpose_body(const float* __restrict__ W,
                                      unsigned short* __restrict__ WT,
                                      int R, int C, int bx, int by, int e,
                                      float* smemf) {
  float (*tile)[65] = (float(*)[65])smemf;
  const int c0 = bx * 64, r0 = by * 64;
  const int lr = threadIdx.x >> 4;    // 0..15
  const int fc = threadIdx.x & 15;    // float4 column
  const float* Wp = W + ((size_t)e * R + r0) * C + c0;
#pragma unroll
  for (int i = 0; i < 4; ++i) {
    int r = lr + i * 16;
    float4 v = *(const float4*)(Wp + (size_t)r * C + fc * 4);
    tile[r][fc * 4 + 0] = v.x; tile[r][fc * 4 + 1] = v.y;
    tile[r][fc * 4 + 2] = v.z; tile[r][fc * 4 + 3] = v.w;
  }
  __syncthreads();
  unsigned short* Op = WT + ((size_t)e * C + c0) * R + r0;
  const int cc0 = threadIdx.x >> 3;   // 0..31
  const int rc = threadIdx.x & 7;     // 8-row source chunk
#pragma unroll
  for (int i = 0; i < 2; ++i) {
    int cc = cc0 + i * 32;
    short8 o;
#pragma unroll
    for (int j = 0; j < 8; ++j) o[j] = (short)f2bf(tile[rc * 8 + j][cc]);
    *(short8*)(Op + (size_t)cc * R + rc * 8) = o;   // 16B/lane, coalesced
  }
}

// ---------------- router body: x fp32 -> xb bf16 + probs + routes -----------
static __device__ void router_body(const float* __restrict__ x,
                                   const float* __restrict__ Wr,
                                   const float* __restrict__ br,
                                   unsigned short* __restrict__ xb,
                                   float* __restrict__ probs_out,
                                   int* __restrict__ routes,
                                   int blk, float* smemf) {
  float (*WrL)[DIN] = (float(*)[DIN])smemf;   // [NEXP][DIN] = 32 KB
  const int tid = threadIdx.x;
  {
    const int r0 = tid * 4;
    float wlo[4][4], whi[4][4];
#pragma unroll
    for (int rr = 0; rr < 4; ++rr) {
      float4 v0 = *(const float4*)(Wr + (size_t)(r0 + rr) * NEXP);
      float4 v1 = *(const float4*)(Wr + (size_t)(r0 + rr) * NEXP + 4);
      wlo[rr][0] = v0.x; wlo[rr][1] = v0.y; wlo[rr][2] = v0.z; wlo[rr][3] = v0.w;
      whi[rr][0] = v1.x; whi[rr][1] = v1.y; whi[rr][2] = v1.z; whi[rr][3] = v1.w;
    }
#pragma unroll
    for (int e = 0; e < 4; ++e) {
      float4 o = { wlo[0][e], wlo[1][e], wlo[2][e], wlo[3][e] };
      *(float4*)&WrL[e][r0] = o;                 // lane stride 16B: no conflict
      float4 o2 = { whi[0][e], whi[1][e], whi[2][e], whi[3][e] };
      *(float4*)&WrL[e + 4][r0] = o2;
    }
  }
  __syncthreads();

  const int lane = tid & 63;
  const int n = blk * 4 + (tid >> 6);
  const float4* xr = (const float4*)(x + (size_t)n * DIN);
  ushort4* xo = (ushort4*)(xb + (size_t)n * DIN);
  float acc[NEXP];
#pragma unroll
  for (int e = 0; e < NEXP; ++e) acc[e] = 0.f;
#pragma unroll
  for (int j = 0; j < 4; ++j) {
    int idx = j * 64 + lane;            // coalesced: 64 consecutive float4
    float4 xv = xr[idx];
    ushort4 o = { f2bf(xv.x), f2bf(xv.y), f2bf(xv.z), f2bf(xv.w) };
    xo[idx] = o;
    int r0 = idx * 4;
#pragma unroll
    for (int e = 0; e < NEXP; ++e) {
      float4 wv = *(const float4*)&WrL[e][r0];
      acc[e] += xv.x * wv.x + xv.y * wv.y + xv.z * wv.z + xv.w * wv.w;
    }
  }
#pragma unroll
  for (int m = 1; m < 64; m <<= 1)
#pragma unroll
    for (int e = 0; e < NEXP; ++e) acc[e] += __shfl_xor(acc[e], m);

  if (lane == 0) {
    float lg[NEXP], p[NEXP];
    float mx = -1e30f;
#pragma unroll
    for (int e = 0; e < NEXP; ++e) { lg[e] = acc[e] + br[e]; mx = fmaxf(mx, lg[e]); }
    float s = 0.f;
#pragma unroll
    for (int e = 0; e < NEXP; ++e) { p[e] = expf(lg[e] - mx); s += p[e]; }
    float inv = 1.f / s;
    int best = 0; float bp = -1.f;
#pragma unroll
    for (int e = 0; e < NEXP; ++e) {
      p[e] *= inv;
      probs_out[(size_t)n * NEXP + e] = p[e];
      if (p[e] > bp) { bp = p[e]; best = e; }   // strict > : first-index tie-break
    }
    routes[n] = best;
  }
}

// ============ prep1: W1-transpose | router (critical path for GEMM1) =======
__global__ __launch_bounds__(256) void prep1_kernel(
    const float* __restrict__ W1, unsigned short* __restrict__ w1t,
    const float* __restrict__ x, const float* __restrict__ Wr,
    const float* __restrict__ br, unsigned short* __restrict__ xb,
    float* __restrict__ probs_out, int* __restrict__ routes) {
  __shared__ float smemf[8192];   // 32 KB union
  const int bid = blockIdx.x;
  if (bid < T1BLK) {
    int e = bid >> 9, rem = bid & 511;   // W1: R=DIN(16 tiles), C=HID(32 tiles)
    transpose_body(W1, w1t, DIN, HID, rem & 31, rem >> 5, e, smemf);
  } else {
    router_body(x, Wr, br, xb, probs_out, routes, bid - T1BLK, smemf);
  }
}

// ====== fused hist + scan + build + pad-fill (ONE single-block kernel) ======
// routes staged in LDS; per-thread (32-token segment) 8-expert counts;
// 8-thread serial prefix over 256 thread-partials; deterministic placement
// with compile-time-indexed per-expert cursors (rule #20); pad slots = -1.
// Replaces hist_scan + build (one launch + cross-block atomics removed).
__global__ __launch_bounds__(256) void hist_build_kernel(
    const int* __restrict__ routes, int* __restrict__ pad_off,
    int2* __restrict__ tile_table, float* __restrict__ counts_out,
    int* __restrict__ sorted) {
  __shared__ int rloc[NTOK];          // 32 KB
  __shared__ int cpre[256][NEXP];     // 8 KB
  __shared__ int tot[NEXP], pstart[NEXP], pend[NEXP];
  const int tid = threadIdx.x;
#pragma unroll
  for (int j = 0; j < 8; ++j)
    ((int4*)rloc)[tid + 256 * j] = ((const int4*)routes)[tid + 256 * j];
  __syncthreads();

  const int t0 = tid * 32;
  int cnt[NEXP];
#pragma unroll
  for (int e = 0; e < NEXP; ++e) cnt[e] = 0;
  for (int i = 0; i < 32; ++i) {
    int r = rloc[t0 + i];
#pragma unroll
    for (int e = 0; e < NEXP; ++e) cnt[e] += (r == e);
  }
#pragma unroll
  for (int e = 0; e < NEXP; ++e) cpre[tid][e] = cnt[e];
  __syncthreads();
  if (tid < NEXP) {                    // 8 threads: serial exclusive prefix
    int run = 0;
    for (int i = 0; i < 256; ++i) { int c = cpre[i][tid]; cpre[i][tid] = run; run += c; }
    tot[tid] = run;
  }
  __syncthreads();
  if (tid == 0) {
    int off = 0, t = 0;
    for (int e = 0; e < NEXP; ++e) {
      int c = tot[e];
      pad_off[e] = off;
      counts_out[e] = (float)c;
      int tiles = (c + BM - 1) / BM;
      pstart[e] = off + c;
      pend[e] = off + tiles * BM;
      for (int i = 0; i < tiles; ++i) { tile_table[t] = make_int2(e, off + i * BM); ++t; }
      off += tiles * BM;
    }
    for (; t < MAXT; ++t) tile_table[t] = make_int2(-1, 0);
  }
  __syncthreads();
  int pos[NEXP];
#pragma unroll
  for (int e = 0; e < NEXP; ++e) pos[e] = pad_off[e] + cpre[tid][e];
  for (int i = 0; i < 32; ++i) {
    int r = rloc[t0 + i];
#pragma unroll
    for (int e = 0; e < NEXP; ++e)     // compile-time index: pos stays in regs
      if (r == e) { sorted[pos[e]] = t0 + i; ++pos[e]; }
  }
#pragma unroll
  for (int e = 0; e < NEXP; ++e)
    for (int i = pstart[e] + tid; i < pend[e]; i += 256) sorted[i] = -1;
}

// ===== grouped GEMM body: m97 structure. 128x128 tile, BK=64, 4 waves, ======
// SINGLE-buffered 32KB LDS, two __syncthreads per K-step, compiler-managed
// waits. TLP (3 blocks/CU) hides the barrier drain (m97/m114: 874-912 TF).
// Wave w owns output rows qm*64.., cols qn*64.. (qm=w>>1, qn=w&1).
// Swizzle (G4): chunk ^= row&7 on pre-swizzled gload source AND
// byte ^= (fr&7)<<4 on ds_read (row bases x16 => row&7 == fr&7) (rule #21).
// MODE 0: A = xb gathered, out = relu(acc+b1) -> bf16 hbuf[token][NDIM]
// MODE 1: A = hbuf gathered, out = acc+b2     -> fp32 out[token][NDIM]
template <int KDIM, int MODE, int NB>
static __device__ void gemm_body(
    short* lds, int bid,
    const unsigned short* __restrict__ A, const unsigned short* __restrict__ WT,
    const float* __restrict__ bias, const int* __restrict__ sorted,
    const int2* __restrict__ tile_table, void* __restrict__ Cout, int NDIM) {
  // T1 bijective XCD swizzle (nwg % 8 == 0)
  const int nwg = NB * MAXT;
  const int swz = (bid & 7) * (nwg >> 3) + (bid >> 3);
  const int2 tt = tile_table[swz / NB];
  if (tt.x < 0) return;
  const int expert = tt.x, mbase = tt.y;
  const int n0 = (swz % NB) * 128;
  const int tid = threadIdx.x, lane = tid & 63, w = tid >> 6;
  const int qm = w >> 1, qn = w & 1;
  const int fr = lane & 15, klo = lane >> 4;

  // ---- staging: 8 x 16B chunks per thread per K-tile (4 A + 4 B) ----
  const short* srcA[4];
  const short* srcB[4];
  int dstA[4], dstB[4];
#pragma unroll
  for (int i = 0; i < 4; ++i) {
    const int ch = i * 256 + tid;                       // 0..1023 (row-major)
    const int row = ch >> 3;                            // 128 rows x 8 chunks
    const int csw = ((ch & 7) ^ (row & 7)) * 8;         // inverse-swizzled source
    int tok = sorted[mbase + row];
    if (tok < 0) tok = 0;                               // pad: dropped at store
    srcA[i] = (const short*)A + (size_t)tok * KDIM + csw;
    srcB[i] = (const short*)WT + ((size_t)expert * NDIM + n0 + row) * KDIM + csw;
    dstA[i] = ch * 8;                                   // linear LDS dest
    dstB[i] = 8192 + ch * 8;
  }

  // ---- fragment ds_read offsets (shorts, swizzled) ----
  const int rsw = (fr & 7) << 4;            // row&7 == fr&7 (bases are x16)
  int aoff[4][2], boff[4][2];
#pragma unroll
  for (int i = 0; i < 4; ++i)
#pragma unroll
    for (int k = 0; k < 2; ++k) {
      int ba = (qm * 64 + i * 16 + fr) * 128 + k * 64 + klo * 16;
      aoff[i][k] = (ba ^ rsw) >> 1;
      int bb = (qn * 64 + i * 16 + fr) * 128 + k * 64 + klo * 16;
      boff[i][k] = ((bb ^ rsw) >> 1) + 8192;
    }

  f32x4 acc[4][4];
#pragma unroll
  for (int mi = 0; mi < 4; ++mi)
#pragma unroll
    for (int nj = 0; nj < 4; ++nj) acc[mi][nj] = (f32x4){0.f, 0.f, 0.f, 0.f};

  constexpr int NKT = KDIM / 64;
  for (int t = 0; t < NKT; ++t) {
    if (t) __syncthreads();               // prev tile's reads done
    const int ko = t * 64;
#pragma unroll
    for (int i = 0; i < 4; ++i) {
      gload_lds16(srcA[i] + ko, &lds[dstA[i]]);
      gload_lds16(srcB[i] + ko, &lds[dstB[i]]);
    }
    __syncthreads();                      // compiler drains vmcnt(0): tile ready
    short8 a[4][2], b[4][2];
#pragma unroll
    for (int i = 0; i < 4; ++i)
#pragma unroll
      for (int k = 0; k < 2; ++k) {
        a[i][k] = *(const short8*)&lds[aoff[i][k]];
        b[i][k] = *(const short8*)&lds[boff[i][k]];
      }
    __builtin_amdgcn_s_setprio(1);
#pragma unroll
    for (int mi = 0; mi < 4; ++mi)
#pragma unroll
      for (int nj = 0; nj < 4; ++nj)
#pragma unroll
        for (int k = 0; k < 2; ++k)
          acc[mi][nj] = __builtin_amdgcn_mfma_f32_16x16x32_bf16(
              a[mi][k], b[nj][k], acc[mi][nj], 0, 0, 0);
    __builtin_amdgcn_s_setprio(0);
  }

  // ---- epilogue: scatter rows to token-indexed buffer ----
  const int fq = lane >> 4;
#pragma unroll
  for (int mi = 0; mi < 4; ++mi) {
    const int rbase = mbase + qm * 64 + mi * 16 + fq * 4;
    int tok[4];
#pragma unroll
    for (int r = 0; r < 4; ++r) tok[r] = sorted[rbase + r];
#pragma unroll
    for (int nj = 0; nj < 4; ++nj) {
      const int col = n0 + qn * 64 + nj * 16 + fr;
      const float bv = bias[(size_t)expert * NDIM + col];
#pragma unroll
      for (int r = 0; r < 4; ++r) {
        if (tok[r] < 0) continue;           // pad row
        float v = acc[mi][nj][r] + bv;
        if (MODE == 0) {
          ((unsigned short*)Cout)[(size_t)tok[r] * NDIM + col] = f2bf(fmaxf(v, 0.f));
        } else {
          ((float*)Cout)[(size_t)tok[r] * NDIM + col] = v;
        }
      }
    }
  }
}

// ===== kernel B: GEMM1 blocks first, then W2-transpose blocks ===============
__global__ __launch_bounds__(256, 3) void gemm1_t2_kernel(
    const unsigned short* __restrict__ xb, const unsigned short* __restrict__ w1t,
    const float* __restrict__ b1, const int* __restrict__ sorted,
    const int2* __restrict__ tile_table, unsigned short* __restrict__ hbuf,
    const float* __restrict__ W2, unsigned short* __restrict__ w2t) {
  __shared__ short lds[16384];   // 32 KB
  const int bid = blockIdx.x;
  if (bid < G1BLK) {
    gemm_body<DIN, 0, HID / 128>(lds, bid, xb, w1t, b1, sorted, tile_table,
                                 (void*)hbuf, HID);
  } else {
    int b = bid - G1BLK;          // W2: R=HID(32 tiles), C=OUTD(16 tiles)
    int e = b >> 9, rem = b & 511;
    transpose_body(W2, w2t, HID, OUTD, rem & 15, rem >> 4, e, (float*)lds);
  }
}

template <int KDIM, int MODE, int NB>
__global__ __launch_bounds__(256, 3) void gemm_moe(
    const unsigned short* __restrict__ A, const unsigned short* __restrict__ WT,
    const float* __restrict__ bias, const int* __restrict__ sorted,
    const int2* __restrict__ tile_table, void* __restrict__ Cout, int NDIM) {
  __shared__ short lds[16384];   // 32 KB
  gemm_body<KDIM, MODE, NB>(lds, blockIdx.x, A, WT, bias, sorted, tile_table,
                            Cout, NDIM);
}

extern "C" void kernel_launch(void* const* d_in, const int* in_sizes, int n_in,
                              void* d_out, int out_size, void* d_ws, size_t ws_size,
                              hipStream_t stream) {
  const float* x  = (const float*)d_in[0];
  const float* Wr = (const float*)d_in[1];
  const float* br = (const float*)d_in[2];
  const float* W1 = (const float*)d_in[3];
  const float* b1 = (const float*)d_in[4];
  const float* W2 = (const float*)d_in[5];
  const float* b2 = (const float*)d_in[6];

  float* out_y      = (float*)d_out;                      // [N,O]
  float* out_probs  = out_y + (size_t)NTOK * OUTD;        // [N,E]
  float* out_counts = out_probs + (size_t)NTOK * NEXP;    // [E]

  char* ws = (char*)d_ws;
  unsigned short* xb   = (unsigned short*)(ws);                                  // 16 MB
  unsigned short* w1t  = (unsigned short*)(ws + 16777216ULL);                    // 32 MB
  unsigned short* w2t  = (unsigned short*)(ws + 50331648ULL);                    // 32 MB
  unsigned short* hbuf = (unsigned short*)(ws + 83886080ULL);                    // 32 MB (token-indexed)
  char* p = ws + 117440512ULL;
  int* routes   = (int*)p; p += 32768;
  int* sorted   = (int*)p; p += (NTOK + NEXP * BM) * 4;
  int* pad_off  = (int*)p; p += 256;
  int2* tt      = (int2*)p;

  prep1_kernel<<<T1BLK + RTBLK, 256, 0, stream>>>(
      W1, w1t, x, Wr, br, xb, out_probs, routes);
  hist_build_kernel<<<1, 256, 0, stream>>>(routes, pad_off, tt, out_counts,
                                           sorted);
  gemm1_t2_kernel<<<G1BLK + T2BLK, 256, 0, stream>>>(
      xb, w1t, b1, sorted, tt, hbuf, W2, w2t);
  gemm_moe<HID, 1, OUTD / 128><<<(OUTD / 128) * MAXT, 256, 0, stream>>>(
      hbuf, w2t, b2, sorted, tt, out_y, OUTD);
}